// Round 8
// baseline (571.744 us; speedup 1.0000x reference)
//
#include <hip/hip_runtime.h>
#include <hip/hip_bf16.h>

// PropNet on MI355X — fp32 in/out, bf16 MFMA compute, fused row-local layers.
// B=4, N=1024, E=8192, NF_IN=32, H=128, NF_OUT=3, pstep=2 (fixed).
//
// R8: INSTRUMENTATION ROUND (sacrificial). Exact R4 arithmetic, but the four
// pipeline kernels are inflated into single large idempotent dispatches
// (grid x REP, block-id masked; all reps write identical values) so each
// exceeds the ~77us poison-fill cutoff and claims a top-5 rocprof slot:
//   k_enc x8 (~120us), first k_eprop x8 (~144us), k_nprop x16 (~80us),
//   k_npropred x16 (~112us). Second k_eprop stays normal (counters from #1).
// This exposes MfmaUtil/VALUBusy/Occupancy/FETCH for the kernels that were
// previously invisible below the fill cutoff. R7 decomposition: pipeline
// ~62us warm, all our dispatches ~105us, ~265us of dur_us is harness tax.

typedef unsigned short u16;
typedef __attribute__((ext_vector_type(8))) __bf16 bf16x8;
typedef __attribute__((ext_vector_type(4))) float f32x4;

#define N_    1024
#define BN    4096      // B*N
#define BE    32768     // B*E
#define LOG_E 13
#define H_    128
#define LSTR  132       // LDS row stride (floats)
#define ECAP  64        // max edges per node in CSR (P(deg>64) ~ 0)
#define ASTR  136       // LDS u16 row stride for bf16 tiles (16B-aligned rows)

// rep-inflation factors (measurement only; reps write identical values)
#define REP_ENC   8
#define REP_EPROP 8
#define REP_NPROP 16
#define REP_NPRED 16

__device__ __forceinline__ u16 f2bf(float f) {
    __bf16 h = (__bf16)f;
    return __builtin_bit_cast(u16, h);
}

__device__ __forceinline__ bf16x8 cvt8(float4 f0, float4 f1) {
    bf16x8 a;
    a[0] = (__bf16)f0.x; a[1] = (__bf16)f0.y; a[2] = (__bf16)f0.z; a[3] = (__bf16)f0.w;
    a[4] = (__bf16)f1.x; a[5] = (__bf16)f1.y; a[6] = (__bf16)f1.z; a[7] = (__bf16)f1.w;
    return a;
}

// A-fragment (8 contiguous k) from fp32 global/LDS pointer (32B-aligned).
__device__ __forceinline__ bf16x8 a_from_f32(const float* p) {
    float4 f0 = *(const float4*)p;
    float4 f1 = *(const float4*)(p + 4);
    return cvt8(f0, f1);
}

// A-fragment from a per-block fp32 LDS tile for K-chunk c, row r.
__device__ __forceinline__ bf16x8 a_from_lds(const float* lds, int r, int quad, int c) {
    return a_from_f32(lds + r * LSTR + c * 32 + quad * 8);
}

// ---- MFMA micro-tiles ------------------------------------------------------
// One K=32 chunk, 4 column-tiles starting at ntb (column-split waves).
__device__ __forceinline__ void mm4(const u16* __restrict__ Wf, int c, int ntb,
                                    bf16x8 a, f32x4* acc, int lane) {
    const u16* wp = Wf + ((size_t)c * 8) * 64 * 8;
    #pragma unroll
    for (int nt = 0; nt < 4; ++nt) {
        bf16x8 bw = *(const bf16x8*)(wp + (size_t)((ntb + nt) * 64 + lane) * 8);
        acc[nt] = __builtin_amdgcn_mfma_f32_16x16x32_bf16(a, bw, acc[nt], 0, 0, 0);
    }
}

// One K=32 chunk, 2 column-tiles starting at ntb.
__device__ __forceinline__ void mm2(const u16* __restrict__ Wf, int c, int ntb,
                                    bf16x8 a, f32x4* acc, int lane) {
    const u16* wp = Wf + ((size_t)c * 8) * 64 * 8;
    #pragma unroll
    for (int nt = 0; nt < 2; ++nt) {
        bf16x8 bw = *(const bf16x8*)(wp + (size_t)((ntb + nt) * 64 + lane) * 8);
        acc[nt] = __builtin_amdgcn_mfma_f32_16x16x32_bf16(a, bw, acc[nt], 0, 0, 0);
    }
}

__device__ __forceinline__ void zacc4(f32x4* acc) {
    #pragma unroll
    for (int t = 0; t < 4; ++t) acc[t] = (f32x4){0.f, 0.f, 0.f, 0.f};
}
__device__ __forceinline__ void zacc2(f32x4* acc) {
    acc[0] = (f32x4){0.f, 0.f, 0.f, 0.f};
    acc[1] = (f32x4){0.f, 0.f, 0.f, 0.f};
}

// bias + ReLU epilogue into fp32 LDS: 4 column-tiles at ntb (16-row slab).
__device__ __forceinline__ void epi4_lds(float* lds, const f32x4* acc,
                                         const float* __restrict__ bias,
                                         int quad, int m, int ntb) {
    #pragma unroll
    for (int nt = 0; nt < 4; ++nt) {
        int col = (ntb + nt) * 16 + m;
        float bv = bias[col];
        #pragma unroll
        for (int i = 0; i < 4; ++i)
            lds[(quad * 4 + i) * LSTR + col] = fmaxf(acc[nt][i] + bv, 0.f);
    }
}

// ---------------------------------------------------------------------------
// k_prep: extract (blocks 0..16383) ∪ weight permutation (blocks 16384..).
// deg must be zeroed (hipMemsetAsync) BEFORE this kernel.
// ---------------------------------------------------------------------------
struct WDesc { const float* src; u16* dst; int K; };
struct WPack { WDesc d[10]; };

__global__ __launch_bounds__(256) void k_prep(WPack P,
                                              const float* __restrict__ Rr,
                                              const float* __restrict__ Rs,
                                              int* __restrict__ recv,
                                              int* __restrict__ send,
                                              int* __restrict__ deg,
                                              int* __restrict__ eidx) {
    int bx = blockIdx.x;
    if (bx >= 16384) {            // ---- weight permutation part ----
        int t = bx - 16384;       // 0..1919, 192 blocks per weight
        WDesc d = P.d[t / 192];
        int i = (t % 192) * 256 + threadIdx.x;
        if (i >= d.K * 128) return;
        int j    = i & 7;
        int lane = (i >> 3) & 63;
        int nt   = (i >> 9) & 7;
        int c    = i >> 12;
        int k = c * 32 + (lane >> 4) * 8 + j;
        int n = nt * 16 + (lane & 15);
        d.dst[i] = f2bf(d.src[k * 128 + n]);
        return;
    }
    // ---- one-hot -> index + receiver CSR part ----
    int wave = threadIdx.x >> 6, lane = threadIdx.x & 63;
    int g = bx * 4 + wave;        // < 2*BE
    const float* src;
    int* dst;
    if (g < BE) { src = Rr + (size_t)g * N_;        dst = recv + g; }
    else        { src = Rs + (size_t)(g - BE) * N_; dst = send + (g - BE); }
    int idx = 0;
    bool done = false;
    #pragma unroll
    for (int it = 0; it < 4; ++it) {
        if (!done) {
            int base = it * 256 + lane * 4;
            float4 v = *(const float4*)(src + base);
            int found = -1;
            if      (v.x != 0.f) found = base;
            else if (v.y != 0.f) found = base + 1;
            else if (v.z != 0.f) found = base + 2;
            else if (v.w != 0.f) found = base + 3;
            unsigned long long msk = __ballot(found >= 0);
            if (msk) {
                int sl = __ffsll((long long)msk) - 1;
                idx = __shfl(found, sl, 64);
                done = true;
            }
        }
    }
    if (lane == 0) {
        *dst = idx;
        if (g < BE) {             // receiver side: CSR build
            int node = (g >> LOG_E) * N_ + idx;
            int pos = atomicAdd(deg + node, 1);
            if (pos < ECAP) eidx[node * ECAP + pos] = g;
        }
    }
}

// ---------------------------------------------------------------------------
// k_enc: node encoder (bxm 0..255) ∪ edge encoder (bxm 256..2303).
// Both 128 threads, 2 waves column-split. Grid = 2304 * REP_ENC.
// ---------------------------------------------------------------------------
__global__ __launch_bounds__(128) void k_enc(
    const float* __restrict__ x,
    const int* __restrict__ recv, const int* __restrict__ send,
    const u16* __restrict__ nW0, const float* __restrict__ nb0,
    const u16* __restrict__ nW1, const float* __restrict__ nb1,
    const u16* __restrict__ nW2, const float* __restrict__ nb2,
    const u16* __restrict__ eW0, const float* __restrict__ eb0,
    const u16* __restrict__ eW1, const float* __restrict__ eb1,
    const u16* __restrict__ eW2, const float* __restrict__ eb2,
    float* __restrict__ nenc_f, u16* __restrict__ nenc_bf,
    u16* __restrict__ eenc)
{
    __shared__ float lds[2][16 * LSTR];
    int tid = threadIdx.x, lane = tid & 63, w = tid >> 6;
    int m = lane & 15, quad = lane >> 4;
    int ntb = w * 4;
    int bxm = blockIdx.x % 2304;      // rep-inflation mask (measurement)
    f32x4 acc[4];

    if (bxm < 256) {              // ---- node encoder ----
        int row16 = bxm * 16;
        zacc4(acc);
        mm4(nW0, 0, ntb, a_from_f32(x + (size_t)(row16 + m) * 32 + quad * 8), acc, lane);
        epi4_lds(lds[0], acc, nb0, quad, m, ntb);
        __syncthreads();

        zacc4(acc);
        #pragma unroll
        for (int c = 0; c < 4; ++c)
            mm4(nW1, c, ntb, a_from_lds(lds[0], m, quad, c), acc, lane);
        epi4_lds(lds[1], acc, nb1, quad, m, ntb);
        __syncthreads();

        zacc4(acc);
        #pragma unroll
        for (int c = 0; c < 4; ++c)
            mm4(nW2, c, ntb, a_from_lds(lds[1], m, quad, c), acc, lane);
        epi4_lds(lds[0], acc, nb2, quad, m, ntb);
        __syncthreads();

        #pragma unroll
        for (int t = 0; t < 16; ++t) {
            int flat = t * 128 + tid, r = flat >> 7, col = flat & 127;
            nenc_f[(size_t)(row16 + r) * H_ + col] = lds[0][r * LSTR + col];
        }
        #pragma unroll
        for (int t = 0; t < 8; ++t) {
            int p = t * 128 + tid, r = p >> 6, c2 = (p & 63) * 2;
            u16 lo = f2bf(lds[0][r * LSTR + c2]);
            u16 hi = f2bf(lds[0][r * LSTR + c2 + 1]);
            *(unsigned*)(nenc_bf + (size_t)(row16 + r) * H_ + c2) =
                (unsigned)lo | ((unsigned)hi << 16);
        }
        return;
    }

    // ---- edge encoder ----
    int row16 = (bxm - 256) * 16;
    int e = row16 + m, b = e >> LOG_E;
    long rr = (long)b * N_ + recv[e];
    long rs = (long)b * N_ + send[e];

    zacc4(acc);
    mm4(eW0, 0, ntb, a_from_f32(x + rr * 32 + quad * 8), acc, lane);
    mm4(eW0, 1, ntb, a_from_f32(x + rs * 32 + quad * 8), acc, lane);
    epi4_lds(lds[0], acc, eb0, quad, m, ntb);
    __syncthreads();

    zacc4(acc);
    #pragma unroll
    for (int c = 0; c < 4; ++c)
        mm4(eW1, c, ntb, a_from_lds(lds[0], m, quad, c), acc, lane);
    epi4_lds(lds[1], acc, eb1, quad, m, ntb);
    __syncthreads();

    zacc4(acc);
    #pragma unroll
    for (int c = 0; c < 4; ++c)
        mm4(eW2, c, ntb, a_from_lds(lds[1], m, quad, c), acc, lane);
    epi4_lds(lds[0], acc, eb2, quad, m, ntb);
    __syncthreads();

    #pragma unroll
    for (int t = 0; t < 8; ++t) {
        int p = t * 128 + tid, r = p >> 6, c2 = (p & 63) * 2;
        u16 lo = f2bf(lds[0][r * LSTR + c2]);
        u16 hi = f2bf(lds[0][r * LSTR + c2 + 1]);
        *(unsigned*)(eenc + (size_t)(row16 + r) * H_ + c2) =
            (unsigned)lo | ((unsigned)hi << 16);
    }
}

// ---------------------------------------------------------------------------
// Prop edge layer: relu(concat(eenc, eff[recv], eff[send]) @ epW + epb)
// -> per-edge effect buffer. 2 waves/block column-split, 16 rows/block.
// Grid = 2048 * REP (first launch) or 2048 (second); bxm = bx & 2047.
// ---------------------------------------------------------------------------
__global__ __launch_bounds__(128) void k_eprop(
    const u16* __restrict__ eenc, const u16* __restrict__ eff_bf,
    const int* __restrict__ recv, const int* __restrict__ send,
    const u16* __restrict__ Wf, const float* __restrict__ bias,
    float* __restrict__ edge_eff)
{
    int tid = threadIdx.x, lane = tid & 63, w = tid >> 6;
    int m = lane & 15, quad = lane >> 4;
    int bxm = blockIdx.x & 2047;      // rep-inflation mask (measurement)
    int row16 = bxm * 16, ntb = w * 4;
    int e = row16 + m;
    long rr = ((long)(e >> LOG_E) * N_ + recv[e]) * H_;
    long rs = ((long)(e >> LOG_E) * N_ + send[e]) * H_;
    f32x4 acc[4];
    zacc4(acc);

    #pragma unroll
    for (int c = 0; c < 4; ++c)
        mm4(Wf, c, ntb,
            *(const bf16x8*)(eenc + (size_t)e * H_ + c * 32 + quad * 8), acc, lane);
    #pragma unroll
    for (int c = 0; c < 4; ++c)
        mm4(Wf, 4 + c, ntb,
            *(const bf16x8*)(eff_bf + rr + c * 32 + quad * 8), acc, lane);
    #pragma unroll
    for (int c = 0; c < 4; ++c)
        mm4(Wf, 8 + c, ntb,
            *(const bf16x8*)(eff_bf + rs + c * 32 + quad * 8), acc, lane);

    #pragma unroll
    for (int nt = 0; nt < 4; ++nt) {
        int col = (ntb + nt) * 16 + m;
        float bv = bias[col];
        #pragma unroll
        for (int i = 0; i < 4; ++i)
            edge_eff[(size_t)(row16 + quad * 4 + i) * H_ + col] =
                fmaxf(acc[nt][i] + bv, 0.f);
    }
}

// ---------------------------------------------------------------------------
// CSR gather-aggregate of incident edge effects into a bf16 LDS tile.
// 256 threads = 16 nodes x 16 col-groups.
// ---------------------------------------------------------------------------
__device__ __forceinline__ void gather_agg(u16* aggl, int row16, int tid, int lane,
                                           const float* __restrict__ edge_eff,
                                           const int* __restrict__ deg,
                                           const int* __restrict__ eidx) {
    int nd = tid >> 4, l = tid & 15;
    int node = row16 + nd;
    int dg = deg[node]; dg = dg < ECAP ? dg : ECAP;
    int ev = eidx[node * ECAP + l];          // preloaded slot l of the list
    int base = lane & 48;                    // 16-lane group start in wave
    float s[8] = {0.f, 0.f, 0.f, 0.f, 0.f, 0.f, 0.f, 0.f};
    int d16 = dg < 16 ? dg : 16;
    int t = 0;
    for (; t + 1 < d16; t += 2) {            // unroll-2: loads pipelined
        int e0 = __shfl(ev, base | t, 64);
        int e1 = __shfl(ev, base | (t + 1), 64);
        const float* p0 = edge_eff + (size_t)e0 * H_ + l * 8;
        const float* p1 = edge_eff + (size_t)e1 * H_ + l * 8;
        float4 a0 = *(const float4*)p0, b0 = *(const float4*)(p0 + 4);
        float4 a1 = *(const float4*)p1, b1 = *(const float4*)(p1 + 4);
        s[0] += a0.x + a1.x; s[1] += a0.y + a1.y;
        s[2] += a0.z + a1.z; s[3] += a0.w + a1.w;
        s[4] += b0.x + b1.x; s[5] += b0.y + b1.y;
        s[6] += b0.z + b1.z; s[7] += b0.w + b1.w;
    }
    if (t < d16) {
        int e0 = __shfl(ev, base | t, 64);
        const float* p0 = edge_eff + (size_t)e0 * H_ + l * 8;
        float4 a0 = *(const float4*)p0, b0 = *(const float4*)(p0 + 4);
        s[0] += a0.x; s[1] += a0.y; s[2] += a0.z; s[3] += a0.w;
        s[4] += b0.x; s[5] += b0.y; s[6] += b0.z; s[7] += b0.w;
        ++t;
    }
    for (; t < dg; ++t) {                    // rare deg>16 tail
        int e0 = eidx[node * ECAP + t];
        const float* p0 = edge_eff + (size_t)e0 * H_ + l * 8;
        float4 a0 = *(const float4*)p0, b0 = *(const float4*)(p0 + 4);
        s[0] += a0.x; s[1] += a0.y; s[2] += a0.z; s[3] += a0.w;
        s[4] += b0.x; s[5] += b0.y; s[6] += b0.z; s[7] += b0.w;
    }
    bf16x8 o;
    #pragma unroll
    for (int j = 0; j < 8; ++j) o[j] = (__bf16)s[j];
    *(bf16x8*)(aggl + nd * ASTR + l * 8) = o;
}

// ---------------------------------------------------------------------------
// Prop node layer (step 1): gather + relu(concat(nenc, agg) @ npW + npb + eff)
// -> nef1 fp32 + bf16. 4 waves/block; grid = 256 * REP_NPROP.
// ---------------------------------------------------------------------------
__global__ __launch_bounds__(256) void k_nprop(
    const u16* __restrict__ nenc_bf, const float* __restrict__ edge_eff,
    const int* __restrict__ deg, const int* __restrict__ eidx,
    const float* __restrict__ eff_f,
    const u16* __restrict__ Wf, const float* __restrict__ bias,
    float* __restrict__ nout_f, u16* __restrict__ nout_bf)
{
    __shared__ u16 aggl[16 * ASTR];
    int tid = threadIdx.x, lane = tid & 63, w = tid >> 6;
    int m = lane & 15, quad = lane >> 4;
    int row16 = (blockIdx.x & 255) * 16;   // rep-inflation mask (measurement)

    gather_agg(aggl, row16, tid, lane, edge_eff, deg, eidx);
    __syncthreads();

    int row = row16 + m, ntb = w * 2;
    f32x4 acc[2];
    zacc2(acc);
    #pragma unroll
    for (int c = 0; c < 4; ++c)
        mm2(Wf, c, ntb,
            *(const bf16x8*)(nenc_bf + (size_t)row * H_ + c * 32 + quad * 8), acc, lane);
    #pragma unroll
    for (int c = 0; c < 4; ++c)
        mm2(Wf, 4 + c, ntb,
            *(const bf16x8*)(aggl + m * ASTR + c * 32 + quad * 8), acc, lane);

    #pragma unroll
    for (int nt = 0; nt < 2; ++nt) {
        int col = (ntb + nt) * 16 + m;
        float bv = bias[col];
        #pragma unroll
        for (int i = 0; i < 4; ++i) {
            int r = row16 + quad * 4 + i;
            float v = fmaxf(acc[nt][i] + bv + eff_f[(size_t)r * H_ + col], 0.f);
            nout_f[(size_t)r * H_ + col] = v;
            nout_bf[(size_t)r * H_ + col] = f2bf(v);
        }
    }
}

// ---------------------------------------------------------------------------
// Prop node layer (step 2) FUSED with the predictor. Row-local chain:
// gather -> np GEMM (+residual, relu) -> pp0 -> pp1 -> [128,3] head -> out.
// Grid = 256 * REP_NPRED.
// ---------------------------------------------------------------------------
__global__ __launch_bounds__(256) void k_npropred(
    const u16* __restrict__ nenc_bf, const float* __restrict__ edge_eff,
    const int* __restrict__ deg, const int* __restrict__ eidx,
    const float* __restrict__ eff_f,
    const u16* __restrict__ Wnp, const float* __restrict__ bnp,
    const u16* __restrict__ Wp0, const float* __restrict__ bp0,
    const u16* __restrict__ Wp1, const float* __restrict__ bp1,
    const float* __restrict__ W2, const float* __restrict__ b2,
    float* __restrict__ out)
{
    __shared__ u16 aggl[16 * ASTR];
    __shared__ u16 vl[16 * ASTR];            // nef2 tile (bf16)
    __shared__ u16 h1[16 * ASTR];            // pp layer-0 output (bf16)
    __shared__ float h2[16 * LSTR];          // pp layer-1 output (fp32)
    int tid = threadIdx.x, lane = tid & 63, w = tid >> 6;
    int m = lane & 15, quad = lane >> 4;
    int row16 = (blockIdx.x & 255) * 16;   // rep-inflation mask (measurement)

    gather_agg(aggl, row16, tid, lane, edge_eff, deg, eidx);
    __syncthreads();

    int row = row16 + m, ntb = w * 2;
    f32x4 acc[2];

    // ---- np layer: v = relu(concat(nenc, agg) @ Wnp + bnp + eff) ----
    zacc2(acc);
    #pragma unroll
    for (int c = 0; c < 4; ++c)
        mm2(Wnp, c, ntb,
            *(const bf16x8*)(nenc_bf + (size_t)row * H_ + c * 32 + quad * 8), acc, lane);
    #pragma unroll
    for (int c = 0; c < 4; ++c)
        mm2(Wnp, 4 + c, ntb,
            *(const bf16x8*)(aggl + m * ASTR + c * 32 + quad * 8), acc, lane);
    #pragma unroll
    for (int nt = 0; nt < 2; ++nt) {
        int col = (ntb + nt) * 16 + m;
        float bv = bnp[col];
        #pragma unroll
        for (int i = 0; i < 4; ++i) {
            int r = quad * 4 + i;
            float v = fmaxf(acc[nt][i] + bv + eff_f[(size_t)(row16 + r) * H_ + col], 0.f);
            vl[r * ASTR + col] = f2bf(v);
        }
    }
    __syncthreads();

    // ---- pp layer 0 (K=256): A = [nenc | v] ----
    zacc2(acc);
    #pragma unroll
    for (int c = 0; c < 4; ++c)
        mm2(Wp0, c, ntb,
            *(const bf16x8*)(nenc_bf + (size_t)row * H_ + c * 32 + quad * 8), acc, lane);
    #pragma unroll
    for (int c = 0; c < 4; ++c)
        mm2(Wp0, 4 + c, ntb,
            *(const bf16x8*)(vl + m * ASTR + c * 32 + quad * 8), acc, lane);
    #pragma unroll
    for (int nt = 0; nt < 2; ++nt) {
        int col = (ntb + nt) * 16 + m;
        float bv = bp0[col];
        #pragma unroll
        for (int i = 0; i < 4; ++i)
            h1[(quad * 4 + i) * ASTR + col] = f2bf(fmaxf(acc[nt][i] + bv, 0.f));
    }
    __syncthreads();

    // ---- pp layer 1 (K=128) ----
    zacc2(acc);
    #pragma unroll
    for (int c = 0; c < 4; ++c)
        mm2(Wp1, c, ntb,
            *(const bf16x8*)(h1 + m * ASTR + c * 32 + quad * 8), acc, lane);
    #pragma unroll
    for (int nt = 0; nt < 2; ++nt) {
        int col = (ntb + nt) * 16 + m;
        float bv = bp1[col];
        #pragma unroll
        for (int i = 0; i < 4; ++i)
            h2[(quad * 4 + i) * LSTR + col] = fmaxf(acc[nt][i] + bv, 0.f);
    }
    __syncthreads();

    // ---- head: out[r,col] = h2[r,:] . W2[:,col] + b2[col] ----
    if (w == 0) {
        int r = lane & 15, col = lane >> 4;
        if (col < 3) {
            float s = 0.f;
            #pragma unroll 8
            for (int k = 0; k < 128; ++k)
                s += h2[r * LSTR + k] * W2[k * 3 + col];
            out[(size_t)(row16 + r) * 3 + col] = s + b2[col];
        }
    }
}

// ---------------------------------------------------------------------------
extern "C" void kernel_launch(void* const* d_in, const int* in_sizes, int n_in,
                              void* d_out, int out_size, void* d_ws, size_t ws_size,
                              hipStream_t stream) {
    (void)in_sizes; (void)n_in; (void)out_size; (void)ws_size;

    const float* x    = (const float*)d_in[0];
    const float* Rr   = (const float*)d_in[1];
    const float* Rs   = (const float*)d_in[2];
    // d_in[3] = pstep (==2, hard-coded)
    const float* neW0 = (const float*)d_in[4];  const float* neb0 = (const float*)d_in[5];
    const float* neW1 = (const float*)d_in[6];  const float* neb1 = (const float*)d_in[7];
    const float* neW2 = (const float*)d_in[8];  const float* neb2 = (const float*)d_in[9];
    const float* eeW0 = (const float*)d_in[10]; const float* eeb0 = (const float*)d_in[11];
    const float* eeW1 = (const float*)d_in[12]; const float* eeb1 = (const float*)d_in[13];
    const float* eeW2 = (const float*)d_in[14]; const float* eeb2 = (const float*)d_in[15];
    const float* npW  = (const float*)d_in[16]; const float* npb  = (const float*)d_in[17];
    const float* epW  = (const float*)d_in[18]; const float* epb  = (const float*)d_in[19];
    const float* ppW0 = (const float*)d_in[20]; const float* ppb0 = (const float*)d_in[21];
    const float* ppW1 = (const float*)d_in[22]; const float* ppb1 = (const float*)d_in[23];
    const float* ppW2 = (const float*)d_in[24]; const float* ppb2 = (const float*)d_in[25];

    char* ws = (char*)d_ws;
    size_t off = 0;
    auto alloc = [&](size_t bytes) -> char* {
        char* p = ws + off;
        off += (bytes + 255) & ~(size_t)255;
        return p;
    };

    u16* f_neW0 = (u16*)alloc(32  * 128 * 2);
    u16* f_neW1 = (u16*)alloc(128 * 128 * 2);
    u16* f_neW2 = (u16*)alloc(128 * 128 * 2);
    u16* f_eeW0 = (u16*)alloc(64  * 128 * 2);
    u16* f_eeW1 = (u16*)alloc(128 * 128 * 2);
    u16* f_eeW2 = (u16*)alloc(128 * 128 * 2);
    u16* f_epW  = (u16*)alloc(384 * 128 * 2);
    u16* f_npW  = (u16*)alloc(256 * 128 * 2);
    u16* f_ppW0 = (u16*)alloc(256 * 128 * 2);
    u16* f_ppW1 = (u16*)alloc(128 * 128 * 2);
    int*   recv = (int*)alloc(BE * 4);
    int*   send = (int*)alloc(BE * 4);
    int*   deg  = (int*)alloc(BN * 4);
    int*   eidx = (int*)alloc((size_t)BN * ECAP * 4);
    float* nenc_f  = (float*)alloc((size_t)BN * H_ * 4);
    u16*   nenc_bf = (u16*)alloc((size_t)BN * H_ * 2);
    float* nef1_f  = (float*)alloc((size_t)BN * H_ * 4);
    u16*   nef1_bf = (u16*)alloc((size_t)BN * H_ * 2);
    float* edge_eff = (float*)alloc((size_t)BE * H_ * 4);
    u16*   eenc = (u16*)alloc((size_t)BE * H_ * 2);

    WPack P;
    P.d[0] = {neW0, f_neW0, 32};
    P.d[1] = {neW1, f_neW1, 128};
    P.d[2] = {neW2, f_neW2, 128};
    P.d[3] = {eeW0, f_eeW0, 64};
    P.d[4] = {eeW1, f_eeW1, 128};
    P.d[5] = {eeW2, f_eeW2, 128};
    P.d[6] = {epW,  f_epW,  384};
    P.d[7] = {npW,  f_npW,  256};
    P.d[8] = {ppW0, f_ppW0, 256};
    P.d[9] = {ppW1, f_ppW1, 128};

    // 0) zero CSR degree counters (graph-capturable memset)
    hipMemsetAsync(deg, 0, BN * 4, stream);

    // 1) extract ∪ weight permutation (not inflatable: CSR atomics)
    k_prep<<<16384 + 1920, 256, 0, stream>>>(P, Rr, Rs, recv, send, deg, eidx);

    // 2) node encoder ∪ edge encoder — inflated x REP_ENC (measurement)
    k_enc<<<2304 * REP_ENC, 128, 0, stream>>>(x, recv, send,
                                          f_neW0, neb0, f_neW1, neb1, f_neW2, neb2,
                                          f_eeW0, eeb0, f_eeW1, eeb1, f_eeW2, eeb2,
                                          nenc_f, nenc_bf, eenc);

    // 3) propagation steps; first eprop / nprop / npropred inflated
    k_eprop<<<2048 * REP_EPROP, 128, 0, stream>>>(eenc, nenc_bf, recv, send,
                                                  f_epW, epb, edge_eff);
    k_nprop<<<256 * REP_NPROP, 256, 0, stream>>>(nenc_bf, edge_eff, deg, eidx, nenc_f,
                                                 f_npW, npb, nef1_f, nef1_bf);
    k_eprop<<<2048, 128, 0, stream>>>(eenc, nef1_bf, recv, send, f_epW, epb, edge_eff);
    k_npropred<<<256 * REP_NPRED, 256, 0, stream>>>(nenc_bf, edge_eff, deg, eidx, nef1_f,
                                                    f_npW, npb, f_ppW0, ppb0,
                                                    f_ppW1, ppb1, ppW2, ppb2,
                                                    (float*)d_out);
}

// Round 9
// 363.569 us; speedup vs baseline: 1.5726x; 1.5726x over previous
//
#include <hip/hip_runtime.h>
#include <hip/hip_bf16.h>

// PropNet on MI355X — fp32 in/out, bf16 MFMA compute, fused row-local layers.
// B=4, N=1024, E=8192, NF_IN=32, H=128, NF_OUT=3, pstep=2 (fixed).
//
// R9: LDS weight staging on the L2-bound edge kernels (R8 counters: eprop
// MfmaUtil 10%, VALUBusy 9%, HBM 19% -> latency/L2-bound on weight re-fetch;
// 2048 blocks x 96KB = 196MB L2 weight traffic).
//  - k_eprop: 512 blocks x 4 waves, each wave owns a 16-row tile (64 rows/
//    block); epW staged to LDS in 3x32KB groups, consumed by all waves.
//    Weight L2 traffic 196 -> 49 MB; B-access latency ~200cyc L2 -> LDS.
//  - k_enc edge path: same structure (512 blocks), eeW staged in 16KB pieces,
//    per-wave bf16 inter-layer tiles (numerically identical rounding).
// Kept: k_prep, CSR aggregation, k_nprop/k_npropred (R4 form), bf16 shadows.

typedef unsigned short u16;
typedef __attribute__((ext_vector_type(8))) __bf16 bf16x8;
typedef __attribute__((ext_vector_type(4))) float f32x4;

#define N_    1024
#define BN    4096      // B*N
#define BE    32768     // B*E
#define LOG_E 13
#define H_    128
#define LSTR  132       // LDS row stride (floats, node path)
#define ECAP  64        // max edges per node in CSR (P(deg>64) ~ 0)
#define ASTR  136       // LDS u16 row stride for bf16 tiles (16B-aligned rows)

__device__ __forceinline__ u16 f2bf(float f) {
    __bf16 h = (__bf16)f;
    return __builtin_bit_cast(u16, h);
}

__device__ __forceinline__ bf16x8 cvt8(float4 f0, float4 f1) {
    bf16x8 a;
    a[0] = (__bf16)f0.x; a[1] = (__bf16)f0.y; a[2] = (__bf16)f0.z; a[3] = (__bf16)f0.w;
    a[4] = (__bf16)f1.x; a[5] = (__bf16)f1.y; a[6] = (__bf16)f1.z; a[7] = (__bf16)f1.w;
    return a;
}

// A-fragment (8 contiguous k) from fp32 global/LDS pointer (32B-aligned).
__device__ __forceinline__ bf16x8 a_from_f32(const float* p) {
    float4 f0 = *(const float4*)p;
    float4 f1 = *(const float4*)(p + 4);
    return cvt8(f0, f1);
}

// A-fragment from a per-block fp32 LDS tile for K-chunk c, row r (node path).
__device__ __forceinline__ bf16x8 a_from_lds(const float* lds, int r, int quad, int c) {
    return a_from_f32(lds + r * LSTR + c * 32 + quad * 8);
}

// ---- MFMA micro-tiles ------------------------------------------------------
// One K=32 chunk (LDS-staged B), all 8 column-tiles. cc = chunk idx in wbuf.
__device__ __forceinline__ void mm8L(const u16* wb, int cc, bf16x8 a,
                                     f32x4* acc, int lane) {
    const u16* wp = wb + cc * 4096;
    #pragma unroll
    for (int nt = 0; nt < 8; ++nt) {
        bf16x8 bw = *(const bf16x8*)(wp + (nt * 64 + lane) * 8);
        acc[nt] = __builtin_amdgcn_mfma_f32_16x16x32_bf16(a, bw, acc[nt], 0, 0, 0);
    }
}

// One K=32 chunk (global B), 2 column-tiles starting at ntb.
__device__ __forceinline__ void mm2(const u16* __restrict__ Wf, int c, int ntb,
                                    bf16x8 a, f32x4* acc, int lane) {
    const u16* wp = Wf + ((size_t)c * 8) * 64 * 8;
    #pragma unroll
    for (int nt = 0; nt < 2; ++nt) {
        bf16x8 bw = *(const bf16x8*)(wp + (size_t)((ntb + nt) * 64 + lane) * 8);
        acc[nt] = __builtin_amdgcn_mfma_f32_16x16x32_bf16(a, bw, acc[nt], 0, 0, 0);
    }
}

__device__ __forceinline__ void zacc8(f32x4* acc) {
    #pragma unroll
    for (int t = 0; t < 8; ++t) acc[t] = (f32x4){0.f, 0.f, 0.f, 0.f};
}
__device__ __forceinline__ void zacc2(f32x4* acc) {
    acc[0] = (f32x4){0.f, 0.f, 0.f, 0.f};
    acc[1] = (f32x4){0.f, 0.f, 0.f, 0.f};
}

// cooperative 16B-unit copy: n16 units, 256 threads
__device__ __forceinline__ void stage_w(u16* dst, const u16* __restrict__ src,
                                        int n16, int tid) {
    for (int t = tid; t < n16; t += 256)
        *(bf16x8*)(dst + t * 8) = *(const bf16x8*)(src + t * 8);
}

// bias+ReLU epilogue into per-wave bf16 tile (stride ASTR).
__device__ __forceinline__ void epi8_bf(u16* t, const f32x4* acc,
                                        const float* __restrict__ bias,
                                        int quad, int m) {
    #pragma unroll
    for (int nt = 0; nt < 8; ++nt) {
        float bv = bias[nt * 16 + m];
        #pragma unroll
        for (int i = 0; i < 4; ++i)
            t[(quad * 4 + i) * ASTR + nt * 16 + m] =
                f2bf(fmaxf(acc[nt][i] + bv, 0.f));
    }
}

// bias+ReLU epilogue into fp32 LDS: 2 column-tiles at ntb (node path).
__device__ __forceinline__ void epi2_lds(float* lds, const f32x4* acc,
                                         const float* __restrict__ bias,
                                         int quad, int m, int ntb) {
    #pragma unroll
    for (int nt = 0; nt < 2; ++nt) {
        int col = (ntb + nt) * 16 + m;
        float bv = bias[col];
        #pragma unroll
        for (int i = 0; i < 4; ++i)
            lds[(quad * 4 + i) * LSTR + col] = fmaxf(acc[nt][i] + bv, 0.f);
    }
}

// ---------------------------------------------------------------------------
// k_prep: extract (blocks 0..16383) ∪ weight permutation (blocks 16384..).
// deg must be zeroed (hipMemsetAsync) BEFORE this kernel.
// ---------------------------------------------------------------------------
struct WDesc { const float* src; u16* dst; int K; };
struct WPack { WDesc d[10]; };

__global__ __launch_bounds__(256) void k_prep(WPack P,
                                              const float* __restrict__ Rr,
                                              const float* __restrict__ Rs,
                                              int* __restrict__ recv,
                                              int* __restrict__ send,
                                              int* __restrict__ deg,
                                              int* __restrict__ eidx) {
    int bx = blockIdx.x;
    if (bx >= 16384) {            // ---- weight permutation part ----
        int t = bx - 16384;       // 0..1919, 192 blocks per weight
        WDesc d = P.d[t / 192];
        int i = (t % 192) * 256 + threadIdx.x;
        if (i >= d.K * 128) return;
        int j    = i & 7;
        int lane = (i >> 3) & 63;
        int nt   = (i >> 9) & 7;
        int c    = i >> 12;
        int k = c * 32 + (lane >> 4) * 8 + j;
        int n = nt * 16 + (lane & 15);
        d.dst[i] = f2bf(d.src[k * 128 + n]);
        return;
    }
    // ---- one-hot -> index + receiver CSR part ----
    int wave = threadIdx.x >> 6, lane = threadIdx.x & 63;
    int g = bx * 4 + wave;        // < 2*BE
    const float* src;
    int* dst;
    if (g < BE) { src = Rr + (size_t)g * N_;        dst = recv + g; }
    else        { src = Rs + (size_t)(g - BE) * N_; dst = send + (g - BE); }
    int idx = 0;
    bool done = false;
    #pragma unroll
    for (int it = 0; it < 4; ++it) {
        if (!done) {
            int base = it * 256 + lane * 4;
            float4 v = *(const float4*)(src + base);
            int found = -1;
            if      (v.x != 0.f) found = base;
            else if (v.y != 0.f) found = base + 1;
            else if (v.z != 0.f) found = base + 2;
            else if (v.w != 0.f) found = base + 3;
            unsigned long long msk = __ballot(found >= 0);
            if (msk) {
                int sl = __ffsll((long long)msk) - 1;
                idx = __shfl(found, sl, 64);
                done = true;
            }
        }
    }
    if (lane == 0) {
        *dst = idx;
        if (g < BE) {             // receiver side: CSR build
            int node = (g >> LOG_E) * N_ + idx;
            int pos = atomicAdd(deg + node, 1);
            if (pos < ECAP) eidx[node * ECAP + pos] = g;
        }
    }
}

// ---------------------------------------------------------------------------
// k_enc: edge encoder (blocks 0..511, 64 rows/block, LDS-staged weights)
//        ∪ node encoder (blocks 512..767, 16 rows, 4-wave col-split).
// 256 threads / 4 waves.
// ---------------------------------------------------------------------------
__global__ __launch_bounds__(256) void k_enc(
    const float* __restrict__ x,
    const int* __restrict__ recv, const int* __restrict__ send,
    const u16* __restrict__ nW0, const float* __restrict__ nb0,
    const u16* __restrict__ nW1, const float* __restrict__ nb1,
    const u16* __restrict__ nW2, const float* __restrict__ nb2,
    const u16* __restrict__ eW0, const float* __restrict__ eb0,
    const u16* __restrict__ eW1, const float* __restrict__ eb1,
    const u16* __restrict__ eW2, const float* __restrict__ eb2,
    float* __restrict__ nenc_f, u16* __restrict__ nenc_bf,
    u16* __restrict__ eenc)
{
    __shared__ union U {
        struct { u16 wbuf[8192]; u16 tile[4][2][16 * ASTR]; } e;  // 16KB + 34KB
        struct { float lds[2][16 * LSTR]; } n;                    // 16.9KB
    } sm;
    int tid = threadIdx.x, lane = tid & 63, w = tid >> 6;
    int m = lane & 15, quad = lane >> 4;

    if (blockIdx.x < 512) {       // ======== edge encoder ========
        int myrow16 = blockIdx.x * 64 + w * 16;
        int e = myrow16 + m, b = e >> LOG_E;
        long rr = (long)b * N_ + recv[e];
        long rs = (long)b * N_ + send[e];
        u16* t0 = sm.e.tile[w][0];
        u16* t1 = sm.e.tile[w][1];
        f32x4 acc[8];

        // ---- layer 0 (K=64: x[rr] | x[rs]) ----
        stage_w(sm.e.wbuf, eW0, 1024, tid);
        __syncthreads();
        zacc8(acc);
        mm8L(sm.e.wbuf, 0, a_from_f32(x + rr * 32 + quad * 8), acc, lane);
        mm8L(sm.e.wbuf, 1, a_from_f32(x + rs * 32 + quad * 8), acc, lane);
        epi8_bf(t0, acc, eb0, quad, m);
        __syncthreads();

        // ---- layer 1 (K=128, staged in 2 halves) ----
        zacc8(acc);
        #pragma unroll
        for (int h = 0; h < 2; ++h) {
            stage_w(sm.e.wbuf, eW1 + h * 8192, 1024, tid);
            __syncthreads();
            #pragma unroll
            for (int cp = 0; cp < 2; ++cp) {
                int c = h * 2 + cp;
                bf16x8 a = *(const bf16x8*)(t0 + m * ASTR + c * 32 + quad * 8);
                mm8L(sm.e.wbuf, cp, a, acc, lane);
            }
            __syncthreads();
        }
        epi8_bf(t1, acc, eb1, quad, m);
        // (no barrier needed: tiles are per-wave; next stage syncs wbuf)

        // ---- layer 2 (K=128, staged in 2 halves) ----
        zacc8(acc);
        #pragma unroll
        for (int h = 0; h < 2; ++h) {
            stage_w(sm.e.wbuf, eW2 + h * 8192, 1024, tid);
            __syncthreads();
            #pragma unroll
            for (int cp = 0; cp < 2; ++cp) {
                int c = h * 2 + cp;
                bf16x8 a = *(const bf16x8*)(t1 + m * ASTR + c * 32 + quad * 8);
                mm8L(sm.e.wbuf, cp, a, acc, lane);
            }
            __syncthreads();
        }
        epi8_bf(t0, acc, eb2, quad, m);

        // coalesced bf16 store of this wave's 16 rows (u32 pairs)
        #pragma unroll
        for (int t = 0; t < 16; ++t)
            *(unsigned*)(eenc + (size_t)(myrow16 + t) * H_ + lane * 2) =
                *(const unsigned*)(t0 + t * ASTR + lane * 2);
        return;
    }

    // ======== node encoder (4 waves col-split, ntb = w*2) ========
    int row16 = (blockIdx.x - 512) * 16, ntb = w * 2;
    f32x4 acc[2];

    zacc2(acc);
    mm2(nW0, 0, ntb, a_from_f32(x + (size_t)(row16 + m) * 32 + quad * 8), acc, lane);
    epi2_lds(sm.n.lds[0], acc, nb0, quad, m, ntb);
    __syncthreads();

    zacc2(acc);
    #pragma unroll
    for (int c = 0; c < 4; ++c)
        mm2(nW1, c, ntb, a_from_lds(sm.n.lds[0], m, quad, c), acc, lane);
    epi2_lds(sm.n.lds[1], acc, nb1, quad, m, ntb);
    __syncthreads();

    zacc2(acc);
    #pragma unroll
    for (int c = 0; c < 4; ++c)
        mm2(nW2, c, ntb, a_from_lds(sm.n.lds[1], m, quad, c), acc, lane);
    epi2_lds(sm.n.lds[0], acc, nb2, quad, m, ntb);
    __syncthreads();

    #pragma unroll
    for (int t = 0; t < 8; ++t) {
        int flat = t * 256 + tid, r = flat >> 7, col = flat & 127;
        nenc_f[(size_t)(row16 + r) * H_ + col] = sm.n.lds[0][r * LSTR + col];
    }
    #pragma unroll
    for (int t = 0; t < 4; ++t) {
        int p = t * 256 + tid, r = p >> 6, c2 = (p & 63) * 2;
        u16 lo = f2bf(sm.n.lds[0][r * LSTR + c2]);
        u16 hi = f2bf(sm.n.lds[0][r * LSTR + c2 + 1]);
        *(unsigned*)(nenc_bf + (size_t)(row16 + r) * H_ + c2) =
            (unsigned)lo | ((unsigned)hi << 16);
    }
}

// ---------------------------------------------------------------------------
// Prop edge layer: relu(concat(eenc, eff[recv], eff[send]) @ epW + epb)
// -> per-edge effect buffer. 512 blocks x 4 waves, 16 rows/wave; epW staged
// into LDS in 3 groups of 4 K-chunks (32KB), shared by all 4 waves.
// ---------------------------------------------------------------------------
__global__ __launch_bounds__(256) void k_eprop(
    const u16* __restrict__ eenc, const u16* __restrict__ eff_bf,
    const int* __restrict__ recv, const int* __restrict__ send,
    const u16* __restrict__ Wf, const float* __restrict__ bias,
    float* __restrict__ edge_eff)
{
    __shared__ u16 wbuf[16384];   // 32 KB: 4 K-chunks of B fragments
    int tid = threadIdx.x, lane = tid & 63, w = tid >> 6;
    int m = lane & 15, quad = lane >> 4;
    int myrow16 = blockIdx.x * 64 + w * 16;
    int e = myrow16 + m;
    long rr = ((long)(e >> LOG_E) * N_ + recv[e]) * H_;
    long rs = ((long)(e >> LOG_E) * N_ + send[e]) * H_;
    f32x4 acc[8];
    zacc8(acc);

    #pragma unroll
    for (int g = 0; g < 3; ++g) {
        stage_w(wbuf, Wf + g * 16384, 2048, tid);
        __syncthreads();
        const u16* abase = (g == 0) ? eenc + (size_t)e * H_
                         : (g == 1) ? eff_bf + rr
                                    : eff_bf + rs;
        #pragma unroll
        for (int c = 0; c < 4; ++c) {
            bf16x8 a = *(const bf16x8*)(abase + c * 32 + quad * 8);
            mm8L(wbuf, c, a, acc, lane);
        }
        __syncthreads();
    }

    #pragma unroll
    for (int nt = 0; nt < 8; ++nt) {
        int col = nt * 16 + m;
        float bv = bias[col];
        #pragma unroll
        for (int i = 0; i < 4; ++i)
            edge_eff[(size_t)(myrow16 + quad * 4 + i) * H_ + col] =
                fmaxf(acc[nt][i] + bv, 0.f);
    }
}

// ---------------------------------------------------------------------------
// CSR gather-aggregate of incident edge effects into a bf16 LDS tile.
// 256 threads = 16 nodes x 16 col-groups.
// ---------------------------------------------------------------------------
__device__ __forceinline__ void gather_agg(u16* aggl, int row16, int tid, int lane,
                                           const float* __restrict__ edge_eff,
                                           const int* __restrict__ deg,
                                           const int* __restrict__ eidx) {
    int nd = tid >> 4, l = tid & 15;
    int node = row16 + nd;
    int dg = deg[node]; dg = dg < ECAP ? dg : ECAP;
    int ev = eidx[node * ECAP + l];          // preloaded slot l of the list
    int base = lane & 48;                    // 16-lane group start in wave
    float s[8] = {0.f, 0.f, 0.f, 0.f, 0.f, 0.f, 0.f, 0.f};
    int d16 = dg < 16 ? dg : 16;
    int t = 0;
    for (; t + 1 < d16; t += 2) {            // unroll-2: loads pipelined
        int e0 = __shfl(ev, base | t, 64);
        int e1 = __shfl(ev, base | (t + 1), 64);
        const float* p0 = edge_eff + (size_t)e0 * H_ + l * 8;
        const float* p1 = edge_eff + (size_t)e1 * H_ + l * 8;
        float4 a0 = *(const float4*)p0, b0 = *(const float4*)(p0 + 4);
        float4 a1 = *(const float4*)p1, b1 = *(const float4*)(p1 + 4);
        s[0] += a0.x + a1.x; s[1] += a0.y + a1.y;
        s[2] += a0.z + a1.z; s[3] += a0.w + a1.w;
        s[4] += b0.x + b1.x; s[5] += b0.y + b1.y;
        s[6] += b0.z + b1.z; s[7] += b0.w + b1.w;
    }
    if (t < d16) {
        int e0 = __shfl(ev, base | t, 64);
        const float* p0 = edge_eff + (size_t)e0 * H_ + l * 8;
        float4 a0 = *(const float4*)p0, b0 = *(const float4*)(p0 + 4);
        s[0] += a0.x; s[1] += a0.y; s[2] += a0.z; s[3] += a0.w;
        s[4] += b0.x; s[5] += b0.y; s[6] += b0.z; s[7] += b0.w;
        ++t;
    }
    for (; t < dg; ++t) {                    // rare deg>16 tail
        int e0 = eidx[node * ECAP + t];
        const float* p0 = edge_eff + (size_t)e0 * H_ + l * 8;
        float4 a0 = *(const float4*)p0, b0 = *(const float4*)(p0 + 4);
        s[0] += a0.x; s[1] += a0.y; s[2] += a0.z; s[3] += a0.w;
        s[4] += b0.x; s[5] += b0.y; s[6] += b0.z; s[7] += b0.w;
    }
    bf16x8 o;
    #pragma unroll
    for (int j = 0; j < 8; ++j) o[j] = (__bf16)s[j];
    *(bf16x8*)(aggl + nd * ASTR + l * 8) = o;
}

// ---------------------------------------------------------------------------
// Prop node layer (step 1): gather + relu(concat(nenc, agg) @ npW + npb + eff)
// -> nef1 fp32 + bf16. 4 waves/block, column-split (ntb = w*2).
// ---------------------------------------------------------------------------
__global__ __launch_bounds__(256) void k_nprop(
    const u16* __restrict__ nenc_bf, const float* __restrict__ edge_eff,
    const int* __restrict__ deg, const int* __restrict__ eidx,
    const float* __restrict__ eff_f,
    const u16* __restrict__ Wf, const float* __restrict__ bias,
    float* __restrict__ nout_f, u16* __restrict__ nout_bf)
{
    __shared__ u16 aggl[16 * ASTR];
    int tid = threadIdx.x, lane = tid & 63, w = tid >> 6;
    int m = lane & 15, quad = lane >> 4;
    int row16 = blockIdx.x * 16;

    gather_agg(aggl, row16, tid, lane, edge_eff, deg, eidx);
    __syncthreads();

    int row = row16 + m, ntb = w * 2;
    f32x4 acc[2];
    zacc2(acc);
    #pragma unroll
    for (int c = 0; c < 4; ++c)
        mm2(Wf, c, ntb,
            *(const bf16x8*)(nenc_bf + (size_t)row * H_ + c * 32 + quad * 8), acc, lane);
    #pragma unroll
    for (int c = 0; c < 4; ++c)
        mm2(Wf, 4 + c, ntb,
            *(const bf16x8*)(aggl + m * ASTR + c * 32 + quad * 8), acc, lane);

    #pragma unroll
    for (int nt = 0; nt < 2; ++nt) {
        int col = (ntb + nt) * 16 + m;
        float bv = bias[col];
        #pragma unroll
        for (int i = 0; i < 4; ++i) {
            int r = row16 + quad * 4 + i;
            float v = fmaxf(acc[nt][i] + bv + eff_f[(size_t)r * H_ + col], 0.f);
            nout_f[(size_t)r * H_ + col] = v;
            nout_bf[(size_t)r * H_ + col] = f2bf(v);
        }
    }
}

// ---------------------------------------------------------------------------
// Prop node layer (step 2) FUSED with the predictor. Row-local chain:
// gather -> np GEMM (+residual, relu) -> pp0 -> pp1 -> [128,3] head -> out.
// ---------------------------------------------------------------------------
__global__ __launch_bounds__(256) void k_npropred(
    const u16* __restrict__ nenc_bf, const float* __restrict__ edge_eff,
    const int* __restrict__ deg, const int* __restrict__ eidx,
    const float* __restrict__ eff_f,
    const u16* __restrict__ Wnp, const float* __restrict__ bnp,
    const u16* __restrict__ Wp0, const float* __restrict__ bp0,
    const u16* __restrict__ Wp1, const float* __restrict__ bp1,
    const float* __restrict__ W2, const float* __restrict__ b2,
    float* __restrict__ out)
{
    __shared__ u16 aggl[16 * ASTR];
    __shared__ u16 vl[16 * ASTR];            // nef2 tile (bf16)
    __shared__ u16 h1[16 * ASTR];            // pp layer-0 output (bf16)
    __shared__ float h2[16 * LSTR];          // pp layer-1 output (fp32)
    int tid = threadIdx.x, lane = tid & 63, w = tid >> 6;
    int m = lane & 15, quad = lane >> 4;
    int row16 = blockIdx.x * 16;

    gather_agg(aggl, row16, tid, lane, edge_eff, deg, eidx);
    __syncthreads();

    int row = row16 + m, ntb = w * 2;
    f32x4 acc[2];

    // ---- np layer: v = relu(concat(nenc, agg) @ Wnp + bnp + eff) ----
    zacc2(acc);
    #pragma unroll
    for (int c = 0; c < 4; ++c)
        mm2(Wnp, c, ntb,
            *(const bf16x8*)(nenc_bf + (size_t)row * H_ + c * 32 + quad * 8), acc, lane);
    #pragma unroll
    for (int c = 0; c < 4; ++c)
        mm2(Wnp, 4 + c, ntb,
            *(const bf16x8*)(aggl + m * ASTR + c * 32 + quad * 8), acc, lane);
    #pragma unroll
    for (int nt = 0; nt < 2; ++nt) {
        int col = (ntb + nt) * 16 + m;
        float bv = bnp[col];
        #pragma unroll
        for (int i = 0; i < 4; ++i) {
            int r = quad * 4 + i;
            float v = fmaxf(acc[nt][i] + bv + eff_f[(size_t)(row16 + r) * H_ + col], 0.f);
            vl[r * ASTR + col] = f2bf(v);
        }
    }
    __syncthreads();

    // ---- pp layer 0 (K=256): A = [nenc | v] ----
    zacc2(acc);
    #pragma unroll
    for (int c = 0; c < 4; ++c)
        mm2(Wp0, c, ntb,
            *(const bf16x8*)(nenc_bf + (size_t)row * H_ + c * 32 + quad * 8), acc, lane);
    #pragma unroll
    for (int c = 0; c < 4; ++c)
        mm2(Wp0, 4 + c, ntb,
            *(const bf16x8*)(vl + m * ASTR + c * 32 + quad * 8), acc, lane);
    #pragma unroll
    for (int nt = 0; nt < 2; ++nt) {
        int col = (ntb + nt) * 16 + m;
        float bv = bp0[col];
        #pragma unroll
        for (int i = 0; i < 4; ++i)
            h1[(quad * 4 + i) * ASTR + col] = f2bf(fmaxf(acc[nt][i] + bv, 0.f));
    }
    __syncthreads();

    // ---- pp layer 1 (K=128) ----
    zacc2(acc);
    #pragma unroll
    for (int c = 0; c < 4; ++c)
        mm2(Wp1, c, ntb,
            *(const bf16x8*)(h1 + m * ASTR + c * 32 + quad * 8), acc, lane);
    #pragma unroll
    for (int nt = 0; nt < 2; ++nt) {
        int col = (ntb + nt) * 16 + m;
        float bv = bp1[col];
        #pragma unroll
        for (int i = 0; i < 4; ++i)
            h2[(quad * 4 + i) * LSTR + col] = fmaxf(acc[nt][i] + bv, 0.f);
    }
    __syncthreads();

    // ---- head: out[r,col] = h2[r,:] . W2[:,col] + b2[col] ----
    if (w == 0) {
        int r = lane & 15, col = lane >> 4;
        if (col < 3) {
            float s = 0.f;
            #pragma unroll 8
            for (int k = 0; k < 128; ++k)
                s += h2[r * LSTR + k] * W2[k * 3 + col];
            out[(size_t)(row16 + r) * 3 + col] = s + b2[col];
        }
    }
}

// ---------------------------------------------------------------------------
extern "C" void kernel_launch(void* const* d_in, const int* in_sizes, int n_in,
                              void* d_out, int out_size, void* d_ws, size_t ws_size,
                              hipStream_t stream) {
    (void)in_sizes; (void)n_in; (void)out_size; (void)ws_size;

    const float* x    = (const float*)d_in[0];
    const float* Rr   = (const float*)d_in[1];
    const float* Rs   = (const float*)d_in[2];
    // d_in[3] = pstep (==2, hard-coded)
    const float* neW0 = (const float*)d_in[4];  const float* neb0 = (const float*)d_in[5];
    const float* neW1 = (const float*)d_in[6];  const float* neb1 = (const float*)d_in[7];
    const float* neW2 = (const float*)d_in[8];  const float* neb2 = (const float*)d_in[9];
    const float* eeW0 = (const float*)d_in[10]; const float* eeb0 = (const float*)d_in[11];
    const float* eeW1 = (const float*)d_in[12]; const float* eeb1 = (const float*)d_in[13];
    const float* eeW2 = (const float*)d_in[14]; const float* eeb2 = (const float*)d_in[15];
    const float* npW  = (const float*)d_in[16]; const float* npb  = (const float*)d_in[17];
    const float* epW  = (const float*)d_in[18]; const float* epb  = (const float*)d_in[19];
    const float* ppW0 = (const float*)d_in[20]; const float* ppb0 = (const float*)d_in[21];
    const float* ppW1 = (const float*)d_in[22]; const float* ppb1 = (const float*)d_in[23];
    const float* ppW2 = (const float*)d_in[24]; const float* ppb2 = (const float*)d_in[25];

    char* ws = (char*)d_ws;
    size_t off = 0;
    auto alloc = [&](size_t bytes) -> char* {
        char* p = ws + off;
        off += (bytes + 255) & ~(size_t)255;
        return p;
    };

    u16* f_neW0 = (u16*)alloc(32  * 128 * 2);
    u16* f_neW1 = (u16*)alloc(128 * 128 * 2);
    u16* f_neW2 = (u16*)alloc(128 * 128 * 2);
    u16* f_eeW0 = (u16*)alloc(64  * 128 * 2);
    u16* f_eeW1 = (u16*)alloc(128 * 128 * 2);
    u16* f_eeW2 = (u16*)alloc(128 * 128 * 2);
    u16* f_epW  = (u16*)alloc(384 * 128 * 2);
    u16* f_npW  = (u16*)alloc(256 * 128 * 2);
    u16* f_ppW0 = (u16*)alloc(256 * 128 * 2);
    u16* f_ppW1 = (u16*)alloc(128 * 128 * 2);
    int*   recv = (int*)alloc(BE * 4);
    int*   send = (int*)alloc(BE * 4);
    int*   deg  = (int*)alloc(BN * 4);
    int*   eidx = (int*)alloc((size_t)BN * ECAP * 4);
    float* nenc_f  = (float*)alloc((size_t)BN * H_ * 4);
    u16*   nenc_bf = (u16*)alloc((size_t)BN * H_ * 2);
    float* nef1_f  = (float*)alloc((size_t)BN * H_ * 4);
    u16*   nef1_bf = (u16*)alloc((size_t)BN * H_ * 2);
    float* edge_eff = (float*)alloc((size_t)BE * H_ * 4);
    u16*   eenc = (u16*)alloc((size_t)BE * H_ * 2);

    WPack P;
    P.d[0] = {neW0, f_neW0, 32};
    P.d[1] = {neW1, f_neW1, 128};
    P.d[2] = {neW2, f_neW2, 128};
    P.d[3] = {eeW0, f_eeW0, 64};
    P.d[4] = {eeW1, f_eeW1, 128};
    P.d[5] = {eeW2, f_eeW2, 128};
    P.d[6] = {epW,  f_epW,  384};
    P.d[7] = {npW,  f_npW,  256};
    P.d[8] = {ppW0, f_ppW0, 256};
    P.d[9] = {ppW1, f_ppW1, 128};

    // 0) zero CSR degree counters (graph-capturable memset)
    hipMemsetAsync(deg, 0, BN * 4, stream);

    // 1) extract ∪ weight permutation
    k_prep<<<16384 + 1920, 256, 0, stream>>>(P, Rr, Rs, recv, send, deg, eidx);

    // 2) edge encoder (LDS-staged) ∪ node encoder
    k_enc<<<512 + 256, 256, 0, stream>>>(x, recv, send,
                                         f_neW0, neb0, f_neW1, neb1, f_neW2, neb2,
                                         f_eeW0, eeb0, f_eeW1, eeb1, f_eeW2, eeb2,
                                         nenc_f, nenc_bf, eenc);

    // 3) propagation steps (pstep = 2); eprop LDS-staged, 64 rows/block
    k_eprop<<<BE / 64, 256, 0, stream>>>(eenc, nenc_bf, recv, send, f_epW, epb, edge_eff);
    k_nprop<<<BN / 16, 256, 0, stream>>>(nenc_bf, edge_eff, deg, eidx, nenc_f,
                                         f_npW, npb, nef1_f, nef1_bf);
    k_eprop<<<BE / 64, 256, 0, stream>>>(eenc, nef1_bf, recv, send, f_epW, epb, edge_eff);
    k_npropred<<<BN / 16, 256, 0, stream>>>(nenc_bf, edge_eff, deg, eidx, nef1_f,
                                            f_npW, npb, f_ppW0, ppb0, f_ppW1, ppb1,
                                            ppW2, ppb2, (float*)d_out);
}